// Round 3
// baseline (753.589 us; speedup 1.0000x reference)
//
#include <hip/hip_runtime.h>

typedef short bf16x8 __attribute__((ext_vector_type(8)));
typedef float f32x4  __attribute__((ext_vector_type(4)));

__device__ __forceinline__ unsigned short f2bf(float f) {
    union { float f; unsigned u; } v; v.f = f;
    unsigned r = v.u + 0x7fffu + ((v.u >> 16) & 1u);
    return (unsigned short)(r >> 16);
}

// ---------------------------------------------------------------------------
// prep_w2t: W2 fp32 [h=128][c=12288] -> W2r bf16 [c2][h], c2 = (c%192)*64+c/192
// (so c2 = ((o*3+k))*64 + i given c = (i*64+o)*3+k). b2r[c2] = b2[c].
// LDS-tiled transpose: coalesced global reads, 128B-chunk writes.
// grid 64 = 32 c-chunks x 2 h-halves, 256 thr.
// ---------------------------------------------------------------------------
__global__ __launch_bounds__(256) void prep_w2t(
    const float* __restrict__ W2, const float* __restrict__ b2,
    unsigned short* __restrict__ W2r, float* __restrict__ b2r)
{
    const int cb = blockIdx.x >> 1;
    const int hh = blockIdx.x & 1;
    const int c0 = cb * 384;
    const int h0 = hh * 64;
    const int tid = threadIdx.x;
    __shared__ __align__(16) unsigned short t[384 * 72];

    for (int h = 0; h < 64; ++h) {
        const float* row = W2 + (size_t)(h0 + h) * 12288 + c0;
        t[tid * 72 + h] = f2bf(row[tid]);
        if (tid < 128) t[(tid + 256) * 72 + h] = f2bf(row[tid + 256]);
    }
    __syncthreads();
    for (int cc = tid; cc < 384; cc += 256) {
        int c = c0 + cc;
        int i = c / 192;
        int rem = c - i * 192;
        int c2 = rem * 64 + i;
        unsigned short* dst = W2r + (size_t)c2 * 128 + h0;
        #pragma unroll
        for (int p = 0; p < 8; ++p)
            *(bf16x8*)(dst + p * 8) = *(const bf16x8*)&t[cc * 72 + p * 8];
        if (hh == 0) b2r[c2] = b2[c];
    }
}

// ---------------------------------------------------------------------------
// fused3: block = (b, 8 l's), 512 thr (8 waves), 2 blocks/CU (78.8 KB LDS).
// Prologue: per-wave hypernet (LN via shfl), bias linear, A-frags.
// Main: per oc (16 o's) x per ih (32 i's): GEMM1 -> wb; conv accumulates;
// then obuf (aliased on wb) -> coalesced drain.
// ---------------------------------------------------------------------------
__global__ __launch_bounds__(512, 4) void fused3(
    const float* __restrict__ x,
    const unsigned short* __restrict__ W2r, const float* __restrict__ b2r,
    const float* __restrict__ z,
    const float* __restrict__ W1,  const float* __restrict__ b1,
    const float* __restrict__ g1,  const float* __restrict__ be1,
    const float* __restrict__ Wb1, const float* __restrict__ bb1,
    const float* __restrict__ gb1, const float* __restrict__ beb1,
    const float* __restrict__ Wb2, const float* __restrict__ bb2,
    float* __restrict__ out)
{
    const int b    = blockIdx.y;
    const int l0   = blockIdx.x * 8;
    const int tid  = threadIdx.x;
    const int wv   = tid >> 6;
    const int lane = tid & 63;
    const int n    = lane & 15;
    const int quad = lane >> 4;

    __shared__ __align__(16) unsigned short xb[10 * 32 * 72];   // 46080 B
    __shared__ __align__(16) unsigned char  wraw[30720];        // wb | obuf | hvs+hbs
    __shared__ float bias_lds[512];                             // 2048 B

    unsigned short* wb  = (unsigned short*)wraw;                // [l][k][o16][i32 pad40]
    float*          obuf = (float*)wraw;                        // [s32][o16][l pad12]
    unsigned short* hvs = (unsigned short*)wraw;                // prologue: 8*128 bf16
    float*          hbs = (float*)(wraw + 4096);                // prologue: 8*128 f32

    // ---- stage x tile early (overlaps hypernet compute) ----
    for (int v = tid; v < 2048; v += 512) {
        int s = v >> 6, i = v & 63;
        const float* xp = x + (((size_t)s * 32 + b) * 64 + i) * 256 + (l0 - 1);
        #pragma unroll
        for (int q = 0; q < 10; ++q) {
            int ll = l0 - 1 + q;
            float val = (ll >= 0 && ll < 256) ? xp[q] : 0.0f;
            xb[(q * 32 + s) * 72 + i] = f2bf(val);
        }
    }

    // ---- hypernet prologue: wave wv -> l = l0 + wv, lane j owns h = {j, j+64}
    {
        const int j  = lane;
        const int bl = b * 256 + l0 + wv;
        float zr[16];
        #pragma unroll
        for (int a = 0; a < 16; ++a) zr[a] = z[bl * 16 + a];

        // weight hypernet
        float p0 = b1[j], p1 = b1[j + 64];
        #pragma unroll
        for (int a = 0; a < 16; ++a) {
            p0 += zr[a] * W1[a * 128 + j];
            p1 += zr[a] * W1[a * 128 + 64 + j];
        }
        float s1 = p0 + p1, s2 = p0 * p0 + p1 * p1;
        #pragma unroll
        for (int m = 1; m < 64; m <<= 1) {
            s1 += __shfl_xor(s1, m, 64);
            s2 += __shfl_xor(s2, m, 64);
        }
        float mu = s1 * (1.0f / 128.0f);
        float var = s2 * (1.0f / 128.0f) - mu * mu;
        float rs = rsqrtf(var + 1e-5f);
        float h0v = fmaxf((p0 - mu) * rs * g1[j] + be1[j], 0.0f);
        float h1v = fmaxf((p1 - mu) * rs * g1[j + 64] + be1[j + 64], 0.0f);
        hvs[wv * 128 + j]      = f2bf(h0v);
        hvs[wv * 128 + 64 + j] = f2bf(h1v);

        // bias hypernet
        p0 = bb1[j]; p1 = bb1[j + 64];
        #pragma unroll
        for (int a = 0; a < 16; ++a) {
            p0 += zr[a] * Wb1[a * 128 + j];
            p1 += zr[a] * Wb1[a * 128 + 64 + j];
        }
        s1 = p0 + p1; s2 = p0 * p0 + p1 * p1;
        #pragma unroll
        for (int m = 1; m < 64; m <<= 1) {
            s1 += __shfl_xor(s1, m, 64);
            s2 += __shfl_xor(s2, m, 64);
        }
        mu = s1 * (1.0f / 128.0f);
        var = s2 * (1.0f / 128.0f) - mu * mu;
        rs = rsqrtf(var + 1e-5f);
        float hb0 = fmaxf((p0 - mu) * rs * gb1[j] + beb1[j], 0.0f);
        float hb1 = fmaxf((p1 - mu) * rs * gb1[j + 64] + beb1[j + 64], 0.0f);
        hbs[wv * 128 + j]      = hb0;
        hbs[wv * 128 + 64 + j] = hb1;
    }
    __syncthreads();

    // ---- bias second linear: lane = o, wave-local hbs (broadcast reads) ----
    {
        float acc = bb2[lane];
        const float* hb = hbs + wv * 128;
        #pragma unroll 8
        for (int h = 0; h < 128; ++h) acc += hb[h] * Wb2[h * 64 + lane];
        bias_lds[wv * 64 + lane] = acc;
    }

    // ---- GEMM1 A-fragments (8 real l rows + 8 zero pad), kept in regs ----
    bf16x8 ah[4];
    if (n < 8) {
        #pragma unroll
        for (int ks = 0; ks < 4; ++ks)
            ah[ks] = *(const bf16x8*)&hvs[n * 128 + ks * 32 + quad * 8];
    } else {
        #pragma unroll
        for (int ks = 0; ks < 4; ++ks) ah[ks] = (bf16x8)0;
    }

    for (int oc = 0; oc < 4; ++oc) {
        f32x4 c0 = {0.f, 0.f, 0.f, 0.f};
        f32x4 c1 = {0.f, 0.f, 0.f, 0.f};

        for (int ih = 0; ih < 2; ++ih) {
            __syncthreads();   // wb free (covers prologue reads on first entry)

            // ---- GEMM1: 96 tiles (o_loc,k,ig), t = wv + 8m, pairs ----
            for (int jj = 0; jj < 6; ++jj) {
                int t0 = wv + 16 * jj, t1 = t0 + 8;
                int ol0 = t0 / 6, r0 = t0 - ol0 * 6, k0 = r0 >> 1, ig0 = r0 & 1;
                int ol1 = t1 / 6, r1 = t1 - ol1 * 6, k1 = r1 >> 1, ig1 = r1 & 1;
                int c2_0 = ((oc * 16 + ol0) * 3 + k0) * 64 + ih * 32 + ig0 * 16 + n;
                int c2_1 = ((oc * 16 + ol1) * 3 + k1) * 64 + ih * 32 + ig1 * 16 + n;

                const unsigned short* bp0 = W2r + (size_t)c2_0 * 128 + quad * 8;
                const unsigned short* bp1 = W2r + (size_t)c2_1 * 128 + quad * 8;
                bf16x8 w00 = *(const bf16x8*)(bp0);
                bf16x8 w10 = *(const bf16x8*)(bp1);
                bf16x8 w01 = *(const bf16x8*)(bp0 + 32);
                bf16x8 w11 = *(const bf16x8*)(bp1 + 32);
                bf16x8 w02 = *(const bf16x8*)(bp0 + 64);
                bf16x8 w12 = *(const bf16x8*)(bp1 + 64);
                bf16x8 w03 = *(const bf16x8*)(bp0 + 96);
                bf16x8 w13 = *(const bf16x8*)(bp1 + 96);

                f32x4 a0 = {0.f, 0.f, 0.f, 0.f};
                f32x4 a1 = {0.f, 0.f, 0.f, 0.f};
                a0 = __builtin_amdgcn_mfma_f32_16x16x32_bf16(ah[0], w00, a0, 0, 0, 0);
                a1 = __builtin_amdgcn_mfma_f32_16x16x32_bf16(ah[0], w10, a1, 0, 0, 0);
                a0 = __builtin_amdgcn_mfma_f32_16x16x32_bf16(ah[1], w01, a0, 0, 0, 0);
                a1 = __builtin_amdgcn_mfma_f32_16x16x32_bf16(ah[1], w11, a1, 0, 0, 0);
                a0 = __builtin_amdgcn_mfma_f32_16x16x32_bf16(ah[2], w02, a0, 0, 0, 0);
                a1 = __builtin_amdgcn_mfma_f32_16x16x32_bf16(ah[2], w12, a1, 0, 0, 0);
                a0 = __builtin_amdgcn_mfma_f32_16x16x32_bf16(ah[3], w03, a0, 0, 0, 0);
                a1 = __builtin_amdgcn_mfma_f32_16x16x32_bf16(ah[3], w13, a1, 0, 0, 0);

                float bv0 = b2r[c2_0];
                float bv1 = b2r[c2_1];
                if (quad < 2) {
                    #pragma unroll
                    for (int r = 0; r < 4; ++r) {
                        int l = quad * 4 + r;
                        wb[((l * 3 + k0) * 16 + ol0) * 40 + ig0 * 16 + n] = f2bf(a0[r] + bv0);
                        wb[((l * 3 + k1) * 16 + ol1) * 40 + ig1 * 16 + n] = f2bf(a1[r] + bv1);
                    }
                }
            }
            __syncthreads();   // wb ready

            // ---- conv partial (this i-half): wave wv owns l = wv ----
            #pragma unroll
            for (int k = 0; k < 3; ++k) {
                bf16x8 bf  = *(const bf16x8*)&wb[((wv * 3 + k) * 16 + n) * 40 + quad * 8];
                bf16x8 xa0 = *(const bf16x8*)&xb[((wv + k) * 32 + n) * 72 + ih * 32 + quad * 8];
                bf16x8 xa1 = *(const bf16x8*)&xb[((wv + k) * 32 + 16 + n) * 72 + ih * 32 + quad * 8];
                c0 = __builtin_amdgcn_mfma_f32_16x16x32_bf16(xa0, bf, c0, 0, 0, 0);
                c1 = __builtin_amdgcn_mfma_f32_16x16x32_bf16(xa1, bf, c1, 0, 0, 0);
            }
        }

        __syncthreads();   // conv reads of wb done -> obuf may overwrite
        {
            float bv = bias_lds[wv * 64 + oc * 16 + n];
            #pragma unroll
            for (int r = 0; r < 4; ++r) {
                int s0 = quad * 4 + r;
                obuf[(s0 * 16 + n) * 12 + wv]      = c0[r] + bv;
                obuf[((s0 + 16) * 16 + n) * 12 + wv] = c1[r] + bv;
            }
        }
        __syncthreads();   // obuf ready
        {
            const int s = tid >> 4, o = tid & 15;
            const float4* src = (const float4*)&obuf[(s * 16 + o) * 12];
            float4 v0 = src[0];
            float4 v1 = src[1];
            float* op = out + (((size_t)s * 32 + b) * 64 + oc * 16 + o) * 256 + l0;
            *(float4*)op = v0;
            *(float4*)(op + 4) = v1;
        }
    }
}

// ---------------------------------------------------------------------------
extern "C" void kernel_launch(void* const* d_in, const int* in_sizes, int n_in,
                              void* d_out, int out_size, void* d_ws, size_t ws_size,
                              hipStream_t stream) {
    const float* x    = (const float*)d_in[0];
    const float* z    = (const float*)d_in[1];
    const float* W1   = (const float*)d_in[2];
    const float* b1   = (const float*)d_in[3];
    const float* g1   = (const float*)d_in[4];
    const float* be1  = (const float*)d_in[5];
    const float* W2   = (const float*)d_in[6];
    const float* b2   = (const float*)d_in[7];
    const float* Wb1  = (const float*)d_in[8];
    const float* bb1  = (const float*)d_in[9];
    const float* gb1  = (const float*)d_in[10];
    const float* beb1 = (const float*)d_in[11];
    const float* Wb2  = (const float*)d_in[12];
    const float* bb2  = (const float*)d_in[13];

    char* ws = (char*)d_ws;
    unsigned short* W2r = (unsigned short*)ws;                          // 3 MB
    float*          b2r = (float*)(ws + (size_t)3 * 1024 * 1024);       // 48 KB

    prep_w2t<<<64, 256, 0, stream>>>(W2, b2, W2r, b2r);

    dim3 grid(32, 32);
    fused3<<<grid, 512, 0, stream>>>(x, W2r, b2r, z,
                                     W1, b1, g1, be1,
                                     Wb1, bb1, gb1, beb1,
                                     Wb2, bb2, (float*)d_out);
}

// Round 5
// 485.748 us; speedup vs baseline: 1.5514x; 1.5514x over previous
//
#include <hip/hip_runtime.h>

typedef short bf16x8 __attribute__((ext_vector_type(8)));
typedef float f32x4  __attribute__((ext_vector_type(4)));

__device__ __forceinline__ unsigned short f2bf(float f) {
    union { float f; unsigned u; } v; v.f = f;
    unsigned r = v.u + 0x7fffu + ((v.u >> 16) & 1u);
    return (unsigned short)(r >> 16);
}

// ---------------------------------------------------------------------------
// prep_w2t: W2 fp32 [h=128][c=12288] -> W2r bf16 [c2][h], c2 = (c%192)*64+c/192
// => c2 = o*192 + k*64 + i for c = (i*64+o)*3+k. b2r[c2] = b2[c].
// ---------------------------------------------------------------------------
__global__ __launch_bounds__(256) void prep_w2t(
    const float* __restrict__ W2, const float* __restrict__ b2,
    unsigned short* __restrict__ W2r, float* __restrict__ b2r)
{
    const int cb = blockIdx.x >> 1;
    const int hh = blockIdx.x & 1;
    const int c0 = cb * 384;
    const int h0 = hh * 64;
    const int tid = threadIdx.x;
    __shared__ __align__(16) unsigned short t[384 * 72];

    for (int h = 0; h < 64; ++h) {
        const float* row = W2 + (size_t)(h0 + h) * 12288 + c0;
        t[tid * 72 + h] = f2bf(row[tid]);
        if (tid < 128) t[(tid + 256) * 72 + h] = f2bf(row[tid + 256]);
    }
    __syncthreads();
    for (int cc = tid; cc < 384; cc += 256) {
        int c = c0 + cc;
        int i = c / 192;
        int rem = c - i * 192;
        int c2 = rem * 64 + i;
        unsigned short* dst = W2r + (size_t)c2 * 128 + h0;
        #pragma unroll
        for (int p = 0; p < 8; ++p)
            *(bf16x8*)(dst + p * 8) = *(const bf16x8*)&t[cc * 72 + p * 8];
        if (hh == 0) b2r[c2] = b2[c];
    }
}

// ---------------------------------------------------------------------------
// hyper2: wave wv handles bl = blockIdx*8+wv. hvb bf16[bl][128], bias_ws f32.
// ---------------------------------------------------------------------------
__global__ __launch_bounds__(512) void hyper2(
    const float* __restrict__ z,
    const float* __restrict__ W1,  const float* __restrict__ b1,
    const float* __restrict__ g1,  const float* __restrict__ be1,
    const float* __restrict__ Wb1, const float* __restrict__ bb1,
    const float* __restrict__ gb1, const float* __restrict__ beb1,
    const float* __restrict__ Wb2, const float* __restrict__ bb2,
    unsigned short* __restrict__ hvb, float* __restrict__ bias_ws)
{
    const int wv = threadIdx.x >> 6;
    const int j  = threadIdx.x & 63;
    const int bl = blockIdx.x * 8 + wv;
    __shared__ float hbs[8 * 128];

    float zr[16];
    #pragma unroll
    for (int a = 0; a < 16; ++a) zr[a] = z[bl * 16 + a];

    // weight head
    float p0 = b1[j], p1 = b1[j + 64];
    #pragma unroll
    for (int a = 0; a < 16; ++a) {
        p0 += zr[a] * W1[a * 128 + j];
        p1 += zr[a] * W1[a * 128 + 64 + j];
    }
    float s1 = p0 + p1, s2 = p0 * p0 + p1 * p1;
    #pragma unroll
    for (int m = 1; m < 64; m <<= 1) {
        s1 += __shfl_xor(s1, m, 64);
        s2 += __shfl_xor(s2, m, 64);
    }
    float mu = s1 * (1.0f / 128.0f);
    float var = s2 * (1.0f / 128.0f) - mu * mu;
    float rs = rsqrtf(var + 1e-5f);
    hvb[bl * 128 + j]      = f2bf(fmaxf((p0 - mu) * rs * g1[j] + be1[j], 0.0f));
    hvb[bl * 128 + 64 + j] = f2bf(fmaxf((p1 - mu) * rs * g1[j + 64] + be1[j + 64], 0.0f));

    // bias head
    p0 = bb1[j]; p1 = bb1[j + 64];
    #pragma unroll
    for (int a = 0; a < 16; ++a) {
        p0 += zr[a] * Wb1[a * 128 + j];
        p1 += zr[a] * Wb1[a * 128 + 64 + j];
    }
    s1 = p0 + p1; s2 = p0 * p0 + p1 * p1;
    #pragma unroll
    for (int m = 1; m < 64; m <<= 1) {
        s1 += __shfl_xor(s1, m, 64);
        s2 += __shfl_xor(s2, m, 64);
    }
    mu = s1 * (1.0f / 128.0f);
    var = s2 * (1.0f / 128.0f) - mu * mu;
    rs = rsqrtf(var + 1e-5f);
    hbs[wv * 128 + j]      = fmaxf((p0 - mu) * rs * gb1[j] + beb1[j], 0.0f);
    hbs[wv * 128 + 64 + j] = fmaxf((p1 - mu) * rs * gb1[j + 64] + beb1[j + 64], 0.0f);
    __syncthreads();

    float acc = bb2[j];
    #pragma unroll 8
    for (int h = 0; h < 128; ++h) acc += hbs[wv * 128 + h] * Wb2[h * 64 + j];
    bias_ws[bl * 64 + j] = acc;
}

// ---------------------------------------------------------------------------
// gemm_w: one chunk of 2048 bl-rows. grid (96 n-tiles, 16 m-tiles), 256 thr.
// C[128 bl][128 c2] = hv @ W2r^T + b2r, written bf16 to wg[bl_local][c2].
// Wave wv owns cols [wv*32, wv*32+32): 8 m-frags x 2 n-frags.
// ---------------------------------------------------------------------------
__global__ __launch_bounds__(256) void gemm_w(
    const unsigned short* __restrict__ hvb_c,
    const unsigned short* __restrict__ W2r,
    const float* __restrict__ b2r,
    unsigned short* __restrict__ wg)
{
    const int nt  = blockIdx.x;     // 0..95
    const int mt  = blockIdx.y;     // 0..15
    const int tid = threadIdx.x;
    const int wv   = tid >> 6;
    const int lane = tid & 63;
    const int n    = lane & 15;
    const int quad = lane >> 4;

    __shared__ __align__(16) unsigned short hs[128 * 136];   // 34816 B, pad 136

    // stage hv tile: 128 rows x 128 h
    for (int v = tid; v < 2048; v += 256) {
        int r = v >> 4, cs = v & 15;
        *(bf16x8*)&hs[r * 136 + cs * 8] =
            *(const bf16x8*)&hvb_c[(size_t)(mt * 128 + r) * 128 + cs * 8];
    }
    __syncthreads();

    f32x4 acc[8][2];
    #pragma unroll
    for (int mf = 0; mf < 8; ++mf) {
        acc[mf][0] = (f32x4){0.f, 0.f, 0.f, 0.f};
        acc[mf][1] = (f32x4){0.f, 0.f, 0.f, 0.f};
    }

    const int ncol0 = nt * 128 + wv * 32 + n;
    for (int ks = 0; ks < 4; ++ks) {
        bf16x8 bf0 = *(const bf16x8*)&W2r[(size_t)ncol0 * 128 + ks * 32 + quad * 8];
        bf16x8 bf1 = *(const bf16x8*)&W2r[(size_t)(ncol0 + 16) * 128 + ks * 32 + quad * 8];
        #pragma unroll
        for (int mf = 0; mf < 8; ++mf) {
            bf16x8 af = *(const bf16x8*)&hs[(mf * 16 + n) * 136 + ks * 32 + quad * 8];
            acc[mf][0] = __builtin_amdgcn_mfma_f32_16x16x32_bf16(af, bf0, acc[mf][0], 0, 0, 0);
            acc[mf][1] = __builtin_amdgcn_mfma_f32_16x16x32_bf16(af, bf1, acc[mf][1], 0, 0, 0);
        }
    }

    const float bv0 = b2r[ncol0];
    const float bv1 = b2r[ncol0 + 16];
    __syncthreads();            // hs reads complete -> reuse as C tile
    #pragma unroll
    for (int mf = 0; mf < 8; ++mf) {
        #pragma unroll
        for (int r = 0; r < 4; ++r) {
            int row = mf * 16 + quad * 4 + r;
            hs[row * 136 + wv * 32 + n]      = f2bf(acc[mf][0][r] + bv0);
            hs[row * 136 + wv * 32 + 16 + n] = f2bf(acc[mf][1][r] + bv1);
        }
    }
    __syncthreads();

    // drain: row-major coalesced, 128B per thread
    {
        const int row = tid >> 1, seg = tid & 1;
        const unsigned short* src = &hs[row * 136 + seg * 64];
        unsigned short* dst = wg + (size_t)(mt * 128 + row) * 12288 + nt * 128 + seg * 64;
        #pragma unroll
        for (int p = 0; p < 8; ++p)
            *(bf16x8*)(dst + p * 8) = *(const bf16x8*)(src + p * 8);
    }
}

// ---------------------------------------------------------------------------
// conv_k: one chunk (8 b's). grid (32 l-tiles, 8 b), 512 thr, wave = l.
// B-frags read directly from wg (16B/lane); xb staged in LDS.
// ---------------------------------------------------------------------------
__global__ __launch_bounds__(512) void conv_k(
    const float* __restrict__ x,
    const unsigned short* __restrict__ wg,     // [2048 bl_local][12288]
    const float* __restrict__ bias_ws,
    float* __restrict__ out, int b0)
{
    const int bl_ = blockIdx.y;               // local b 0..7
    const int b   = b0 + bl_;
    const int l0  = blockIdx.x * 8;
    const int tid = threadIdx.x;
    const int wv   = tid >> 6;
    const int lane = tid & 63;
    const int n    = lane & 15;
    const int quad = lane >> 4;

    __shared__ __align__(16) unsigned short xb[10 * 32 * 72];  // 46080 B
    __shared__ __align__(16) float obuf[32 * 16 * 12];         // 24576 B
    __shared__ float bias_lds[512];                            // 2048 B

    bias_lds[tid] = bias_ws[(size_t)(b * 256 + l0) * 64 + tid];

    for (int v = tid; v < 2048; v += 512) {
        int s = v >> 6, i = v & 63;
        const float* xp = x + (((size_t)s * 32 + b) * 64 + i) * 256 + (l0 - 1);
        #pragma unroll
        for (int q = 0; q < 10; ++q) {
            int ll = l0 - 1 + q;
            float val = (ll >= 0 && ll < 256) ? xp[q] : 0.0f;
            xb[(q * 32 + s) * 72 + i] = f2bf(val);
        }
    }
    __syncthreads();

    const unsigned short* wp = wg + (size_t)(bl_ * 256 + l0 + wv) * 12288;

    for (int oc = 0; oc < 4; ++oc) {
        f32x4 c0 = {0.f, 0.f, 0.f, 0.f};
        f32x4 c1 = {0.f, 0.f, 0.f, 0.f};
        #pragma unroll
        for (int k = 0; k < 3; ++k) {
            #pragma unroll
            for (int ih = 0; ih < 2; ++ih) {
                bf16x8 bfr = *(const bf16x8*)&wp[(oc * 16 + n) * 192 + k * 64 + ih * 32 + quad * 8];
                bf16x8 xa0 = *(const bf16x8*)&xb[((wv + k) * 32 + n) * 72 + ih * 32 + quad * 8];
                bf16x8 xa1 = *(const bf16x8*)&xb[((wv + k) * 32 + 16 + n) * 72 + ih * 32 + quad * 8];
                c0 = __builtin_amdgcn_mfma_f32_16x16x32_bf16(xa0, bfr, c0, 0, 0, 0);
                c1 = __builtin_amdgcn_mfma_f32_16x16x32_bf16(xa1, bfr, c1, 0, 0, 0);
            }
        }

        __syncthreads();   // prev drain done (oc=0: covered by xb barrier)
        {
            float bv = bias_lds[wv * 64 + oc * 16 + n];
            #pragma unroll
            for (int r = 0; r < 4; ++r) {
                int s0 = quad * 4 + r;
                obuf[(s0 * 16 + n) * 12 + wv]        = c0[r] + bv;
                obuf[((s0 + 16) * 16 + n) * 12 + wv] = c1[r] + bv;
            }
        }
        __syncthreads();   // obuf ready
        {
            const int s = tid >> 4, o = tid & 15;
            const float4* src = (const float4*)&obuf[(s * 16 + o) * 12];
            float4 v0 = src[0];
            float4 v1 = src[1];
            float* op = out + (((size_t)s * 32 + b) * 64 + oc * 16 + o) * 256 + l0;
            *(float4*)op = v0;
            *(float4*)(op + 4) = v1;
        }
    }
}

// ---------------------------------------------------------------------------
extern "C" void kernel_launch(void* const* d_in, const int* in_sizes, int n_in,
                              void* d_out, int out_size, void* d_ws, size_t ws_size,
                              hipStream_t stream) {
    const float* x    = (const float*)d_in[0];
    const float* z    = (const float*)d_in[1];
    const float* W1   = (const float*)d_in[2];
    const float* b1   = (const float*)d_in[3];
    const float* g1   = (const float*)d_in[4];
    const float* be1  = (const float*)d_in[5];
    const float* W2   = (const float*)d_in[6];
    const float* b2   = (const float*)d_in[7];
    const float* Wb1  = (const float*)d_in[8];
    const float* bb1  = (const float*)d_in[9];
    const float* gb1  = (const float*)d_in[10];
    const float* beb1 = (const float*)d_in[11];
    const float* Wb2  = (const float*)d_in[12];
    const float* bb2  = (const float*)d_in[13];

    // Workspace layout (bytes), non-overlapping:
    //   W2r     [0            , 3,145,728)   12288*128 bf16
    //   b2r     [3,145,728    , 3,194,880)   12288 f32
    //   hvb     [3,211,264    , 5,308,416)   8192*128 bf16   (3 MB + 64 KB)
    //   bias_ws [5,308,416    , 7,405,568)   8192*64 f32
    //   wg      [7,405,568    , 57,737,216)  2048*12288 bf16 (48 MB)
    char* ws = (char*)d_ws;
    unsigned short* W2r     = (unsigned short*)ws;
    float*          b2r     = (float*)(ws + (size_t)3145728);
    unsigned short* hvb     = (unsigned short*)(ws + (size_t)3211264);
    float*          bias_ws = (float*)(ws + (size_t)5308416);
    unsigned short* wg      = (unsigned short*)(ws + (size_t)7405568);

    prep_w2t<<<64, 256, 0, stream>>>(W2, b2, W2r, b2r);
    hyper2<<<1024, 512, 0, stream>>>(z, W1, b1, g1, be1,
                                     Wb1, bb1, gb1, beb1, Wb2, bb2,
                                     hvb, bias_ws);

    for (int c = 0; c < 4; ++c) {
        gemm_w<<<dim3(96, 16), 256, 0, stream>>>(hvb + (size_t)c * 2048 * 128,
                                                 W2r, b2r, wg);
        conv_k<<<dim3(32, 8), 512, 0, stream>>>(x, wg, bias_ws, (float*)d_out, c * 8);
    }
}